// Round 3
// baseline (565.383 us; speedup 1.0000x reference)
//
#include <hip/hip_runtime.h>

#define DEVI __device__ __forceinline__

typedef __bf16 bf16x8 __attribute__((ext_vector_type(8)));
typedef float f32x4 __attribute__((ext_vector_type(4)));

#define WAIT_VM(n) asm volatile("s_waitcnt vmcnt(" #n ")" ::: "memory")

// ---------- exact bf16 RNE helpers ----------
DEVI unsigned short f2bf(float f) {
  unsigned u = __float_as_uint(f);
  u = (u + 0x7FFFu + ((u >> 16) & 1u)) >> 16;
  return (unsigned short)u;
}
DEVI float bf2f(unsigned short h) { return __uint_as_float(((unsigned)h) << 16); }
DEVI float bf16r(float f) { return bf2f(f2bf(f)); }

// ---------- fast MXINT8 scale from block amax (amax normal, >0) ----------
DEVI void mx_scales(float amax, float& scale, float& inv) {
  unsigned eb = __float_as_uint(amax) & 0x7f800000u;
  scale = __uint_as_float(eb - (6u << 23));          // 2^(e-6)
  inv   = __uint_as_float((260u << 23) - eb);        // 2^(6-e)
}

DEVI unsigned short quantv(float v, float scale, float inv) {
  float qv = rintf(v * inv);                          // RNE, matches jnp.round
  qv = fminf(fmaxf(qv, -128.f), 127.f);
  return f2bf(qv * scale);                            // exact in bf16
}

DEVI void quant8(const float* h, float amax, unsigned short* q) {
  if (amax > 0.f) {
    float scale, inv;
    mx_scales(amax, scale, inv);
#pragma unroll
    for (int k = 0; k < 8; ++k) q[k] = quantv(h[k], scale, inv);
  } else {
#pragma unroll
    for (int k = 0; k < 8; ++k) q[k] = 0;
  }
}

// ---------- 16-lane (DPP row) max reduction on the VALU pipe ----------
template <int N>
DEVI float qmax_step(float x) {
  int y = __builtin_amdgcn_update_dpp(0, __float_as_int(x), 0x120 | N, 0xF, 0xF, true);
  return fmaxf(x, __int_as_float(y));
}
DEVI float quad_row_max(float x) {
  x = qmax_step<1>(x);
  x = qmax_step<2>(x);
  x = qmax_step<4>(x);
  x = qmax_step<8>(x);
  return x;
}

// ---------- async global->LDS 16B ----------
DEVI void gl2lds16(const void* g, void* l) {
  __builtin_amdgcn_global_load_lds(
      (__attribute__((address_space(1))) void*)const_cast<void*>(g),
      (__attribute__((address_space(3))) void*)l, 16, 0, 0);
}

DEVI uint4 pack8(const unsigned short* q) {
  uint4 o;
  o.x = (unsigned)q[0] | ((unsigned)q[1] << 16);
  o.y = (unsigned)q[2] | ((unsigned)q[3] << 16);
  o.z = (unsigned)q[4] | ((unsigned)q[5] << 16);
  o.w = (unsigned)q[6] | ((unsigned)q[7] << 16);
  return o;
}

// ---------- merged prep: W1 quant | W2 quant | LN+quant in ONE dispatch ----------
__global__ __launch_bounds__(256) void prep_k(const float* __restrict__ W1,
                                              const float* __restrict__ W2,
                                              const float* __restrict__ X,
                                              const float* __restrict__ lw,
                                              const float* __restrict__ lb,
                                              unsigned short* __restrict__ qW1,
                                              unsigned short* __restrict__ qW2,
                                              unsigned short* __restrict__ a1) {
  __shared__ float red[4];
  const int bid = blockIdx.x;
  const int t = threadIdx.x;
  if (bid < 16384) {
    const float* src = (bid < 8192) ? W1 : W2;
    unsigned short* dst = (bid < 8192) ? qW1 : qW2;
    size_t idx = (size_t)(bid & 8191) * 256 + t;   // 8 elems/thread
    float4 v0 = ((const float4*)src)[idx * 2];
    float4 v1 = ((const float4*)src)[idx * 2 + 1];
    float h[8] = {v0.x, v0.y, v0.z, v0.w, v1.x, v1.y, v1.z, v1.w};
    float amax = 0.f;
#pragma unroll
    for (int k = 0; k < 8; ++k) amax = fmaxf(amax, fabsf(h[k]));
    amax = fmaxf(amax, __shfl_xor(amax, 1));   // 4 consecutive lanes = one 32-block
    amax = fmaxf(amax, __shfl_xor(amax, 2));
    unsigned short q[8];
    quant8(h, amax, q);
    ((uint4*)dst)[idx] = pack8(q);
  } else {
    const int H = 2048;
    const int row = bid - 16384;
    const int lane = t & 63, wave = t >> 6;
    const float* xr = X + (size_t)row * H;
    float4 v0 = ((const float4*)xr)[2 * t];
    float4 v1 = ((const float4*)xr)[2 * t + 1];
    float x[8] = {bf16r(v0.x), bf16r(v0.y), bf16r(v0.z), bf16r(v0.w),
                  bf16r(v1.x), bf16r(v1.y), bf16r(v1.z), bf16r(v1.w)};
    float s = 0.f;
#pragma unroll
    for (int k = 0; k < 8; ++k) s += x[k];
#pragma unroll
    for (int o = 32; o; o >>= 1) s += __shfl_xor(s, o);
    if (lane == 0) red[wave] = s;
    __syncthreads();
    float mu = (red[0] + red[1] + red[2] + red[3]) * (1.0f / H);
    __syncthreads();
    float v = 0.f;
#pragma unroll
    for (int k = 0; k < 8; ++k) { float d = x[k] - mu; v += d * d; }
#pragma unroll
    for (int o = 32; o; o >>= 1) v += __shfl_xor(v, o);
    if (lane == 0) red[wave] = v;
    __syncthreads();
    float var = (red[0] + red[1] + red[2] + red[3]) * (1.0f / H);
    float rstd = 1.0f / sqrtf(var + 1e-5f);
    float h[8];
    float amax = 0.f;
#pragma unroll
    for (int k = 0; k < 8; ++k) {
      int col = t * 8 + k;
      h[k] = bf16r((x[k] - mu) * rstd * lw[col] + lb[col]);
      amax = fmaxf(amax, fabsf(h[k]));
    }
    amax = fmaxf(amax, __shfl_xor(amax, 1));
    amax = fmaxf(amax, __shfl_xor(amax, 2));
    unsigned short q[8];
    quant8(h, amax, q);
    ((uint4*)(a1 + (size_t)row * H))[t] = pack8(q);
  }
}

// ---------- GEMM: C[m,n] = sum_k A[m,k]*B[n,k], A/B bf16, fp32 acc ----------
// 256 x (NREP*64) tile, BK=32, 512 threads = 8 waves (2M x 4N), per-wave
// output 128 x (NREP*16): M_rep=8, N_rep=NREP. GEMM1: NREP=4 (256x256),
// GEMM2: NREP=2 (256x128 -> 256 blocks, full chip).
//
// Pipeline: 4 LDS buffers (tile t in buf t&3), stage tile t+3 during tile t,
// counted vmcnt(2L) at tile end (L = lines/tile = 2+BN/128) -> never drains
// in steady state. ONE barrier per K-tile:
//   WAR: writes to buf (t+3)&3 = (t-1)&3 issue after the barrier that ends
//        tile t-1, whose frag reads drained before it (lgkm waits precede use).
//   RAW: vmcnt(2L) guarantees tile t+1's lines landed before the barrier.
// All 12 frag ds_reads issue before cluster-0 MFMA; compiler's in-order
// fine-grained lgkm waits leave cluster-1's 4 A-reads in flight under the
// first 16 MFMAs (no manual lgkmcnt -> rule 18 not triggered).
//
// LDS rows are 32 ushorts (64 B); 4 chunks of 8. Swizzle: chunk c stored at
// position c ^ ((row>>1)&3). Frag read: lane(quad q, lr) reads logical chunk
// q at pos q^((lr>>1)&3) -> 8 lanes per 16B bank slot = b128 minimum (free).
// Staging: LDS dest linear, global source chunk = pos ^ ((row>>1)&3).
// MODE 1: h = bf16(gelu_tanh(bf16(y+bias))) then fused MX-quant (DPP) -> bf16
// MODE 2: out = bf16(bf16(resid) + bf16(y + bias)) -> float
template <int MODE, int NREP>
__global__ __launch_bounds__(512, 2) void gemm_mx(const unsigned short* __restrict__ A,
                                                  const unsigned short* __restrict__ B,
                                                  int M, int N, int K,
                                                  const float* __restrict__ bias,
                                                  const float* __restrict__ resid,
                                                  void* __restrict__ outp) {
  constexpr int BN = NREP * 64;
  constexpr int BT_B = BN * 32;                  // ushorts per B tile buffer
  __shared__ __align__(16) unsigned short As[4 * 256 * 32];  // 64 KiB
  __shared__ __align__(16) unsigned short Bs[4 * BT_B];      // 64 / 32 KiB

  const int tid = threadIdx.x;
  const int lane = tid & 63;
  const int lr = lane & 15;
  const int quad = lane >> 4;
  const int wave = tid >> 6;
  const int wm = wave >> 2;          // 0..1
  const int wn = wave & 3;           // 0..3

  // XCD-bijective block swizzle (nwg % 8 == 0 for both GEMMs)
  const int gx = gridDim.x;
  const int nwg = gx * gridDim.y;
  int lin = blockIdx.y * gx + blockIdx.x;
  lin = (lin & 7) * (nwg >> 3) + (lin >> 3);
  const int m0 = (lin / gx) * 256;
  const int n0 = (lin % gx) * BN;

  // frag-read bases (ushort units within a tile buffer)
  const int ch = quad ^ ((lr >> 1) & 3);
  const int arow = (wm * 128 + lr) * 32 + ch * 8;
  const int brow = (wn * (NREP * 16) + lr) * 32 + ch * 8;

  // staging: thread tid writes LDS ushorts [line*4096 + tid*8 ..+7]
  //   -> row = line*128 + (tid>>2), pos = tid&3; source chunk = pos^((row>>1)&3)
  const int srow = tid >> 2;                     // 0..127
  const int sch = (tid & 3) ^ ((tid >> 3) & 3);
  const size_t aoffL0 = (size_t)(m0 + srow) * K + sch * 8;
  const size_t aoffL1 = (size_t)(m0 + 128 + srow) * K + sch * 8;
  const size_t boffL0 = (size_t)(n0 + srow) * K + sch * 8;
  size_t boffL1 = 0;
  if constexpr (NREP == 4) boffL1 = (size_t)(n0 + 128 + srow) * K + sch * 8;
  const int lb = (tid & ~63) * 8;                // wave-uniform LDS base (ushorts)

  const int NT = K >> 5;

  f32x4 acc[8][NREP];
#pragma unroll
  for (int i = 0; i < 8; ++i)
#pragma unroll
    for (int j = 0; j < NREP; ++j) acc[i][j] = (f32x4){0.f, 0.f, 0.f, 0.f};

  // prologue: stage tiles 0..2
#pragma unroll
  for (int pt = 0; pt < 3; ++pt) {
    const size_t kb = (size_t)pt * 32;
    gl2lds16(A + aoffL0 + kb, As + pt * 8192 + lb);
    gl2lds16(A + aoffL1 + kb, As + pt * 8192 + 4096 + lb);
    gl2lds16(B + boffL0 + kb, Bs + pt * BT_B + lb);
    if constexpr (NREP == 4) gl2lds16(B + boffL1 + kb, Bs + pt * BT_B + 4096 + lb);
  }
  if constexpr (NREP == 4) WAIT_VM(8); else WAIT_VM(6);   // tile 0 resident
  __builtin_amdgcn_s_barrier();

  for (int t = 0; t < NT; ++t) {
    const unsigned short* Ab = As + (t & 3) * 8192;
    const unsigned short* Bb = Bs + (t & 3) * BT_B;
    bf16x8 a0[4], a1[4], bq[NREP];
#pragma unroll
    for (int i = 0; i < 4; ++i) a0[i] = *(const bf16x8*)(Ab + arow + i * 512);
#pragma unroll
    for (int j = 0; j < NREP; ++j) bq[j] = *(const bf16x8*)(Bb + brow + j * 512);
    const bool pf = (t + 3) < NT;
    const int nb = (t + 3) & 3;
    const size_t kb = (size_t)(t + 3) * 32;
    if (pf) {
      gl2lds16(A + aoffL0 + kb, As + nb * 8192 + lb);
      gl2lds16(A + aoffL1 + kb, As + nb * 8192 + 4096 + lb);
    }
#pragma unroll
    for (int i = 0; i < 4; ++i) a1[i] = *(const bf16x8*)(Ab + arow + 2048 + i * 512);
    if (pf) {
      gl2lds16(B + boffL0 + kb, Bs + nb * BT_B + lb);
      if constexpr (NREP == 4) gl2lds16(B + boffL1 + kb, Bs + nb * BT_B + 4096 + lb);
    }
    __builtin_amdgcn_s_setprio(1);
#pragma unroll
    for (int i = 0; i < 4; ++i)
#pragma unroll
      for (int j = 0; j < NREP; ++j)
        acc[i][j] = __builtin_amdgcn_mfma_f32_16x16x32_bf16(a0[i], bq[j], acc[i][j], 0, 0, 0);
    __builtin_amdgcn_s_setprio(0);
    __builtin_amdgcn_s_setprio(1);
#pragma unroll
    for (int i = 0; i < 4; ++i)
#pragma unroll
      for (int j = 0; j < NREP; ++j)
        acc[i + 4][j] = __builtin_amdgcn_mfma_f32_16x16x32_bf16(a1[i], bq[j], acc[i + 4][j], 0, 0, 0);
    __builtin_amdgcn_s_setprio(0);
    // tile-end wait: tile t+1 resident; keep newer lines in flight
    if (pf) {
      if constexpr (NREP == 4) WAIT_VM(8); else WAIT_VM(6);
    } else if (t + 2 < NT) {
      if constexpr (NREP == 4) WAIT_VM(4); else WAIT_VM(3);
    } else {
      WAIT_VM(0);
    }
    __builtin_amdgcn_s_barrier();
    __builtin_amdgcn_sched_barrier(0);
  }

  // epilogue: D mapping col = lane&15, row = quad*4 + reg   [m89-verified]
  if (MODE == 1) {
#pragma unroll
    for (int i = 0; i < 8; ++i) {
#pragma unroll
      for (int r = 0; r < 4; ++r) {
        const int gm = m0 + wm * 128 + i * 16 + quad * 4 + r;
        float g[4];
#pragma unroll
        for (int j = 0; j < 4; ++j) {
          float tt = bf16r(acc[i][j][r] + bias[n0 + wn * 64 + j * 16 + lr]);
          float u = 0.7978845608028654f * (tt + 0.044715f * tt * tt * tt);
          g[j] = bf16r(0.5f * tt * (1.0f + tanhf(u)));
        }
        // fused MX quant: 32-col block = {j0,j1} / {j2,j3} over this quad's lanes
        float a = quad_row_max(fmaxf(fabsf(g[0]), fabsf(g[1])));
        float b = quad_row_max(fmaxf(fabsf(g[2]), fabsf(g[3])));
        unsigned short q[4];
        if (a > 0.f) {
          float sc2, iv; mx_scales(a, sc2, iv);
          q[0] = quantv(g[0], sc2, iv); q[1] = quantv(g[1], sc2, iv);
        } else { q[0] = q[1] = 0; }
        if (b > 0.f) {
          float sc2, iv; mx_scales(b, sc2, iv);
          q[2] = quantv(g[2], sc2, iv); q[3] = quantv(g[3], sc2, iv);
        } else { q[2] = q[3] = 0; }
        unsigned short* orow = (unsigned short*)outp + (size_t)gm * N + n0 + wn * 64 + lr;
#pragma unroll
        for (int j = 0; j < 4; ++j) orow[j * 16] = q[j];
      }
    }
  } else {
#pragma unroll
    for (int i = 0; i < 8; ++i) {
#pragma unroll
      for (int j = 0; j < NREP; ++j) {
#pragma unroll
        for (int r = 0; r < 4; ++r) {
          int gm = m0 + wm * 128 + i * 16 + quad * 4 + r;
          int gn = n0 + wn * (NREP * 16) + j * 16 + lr;
          float h = bf16r(acc[i][j][r] + bias[gn]);
          float rr = bf16r(resid[(size_t)gm * N + gn]);
          ((float*)outp)[(size_t)gm * N + gn] = bf16r(rr + h);
        }
      }
    }
  }
  (void)M;
}

extern "C" void kernel_launch(void* const* d_in, const int* in_sizes, int n_in,
                              void* d_out, int out_size, void* d_ws, size_t ws_size,
                              hipStream_t stream) {
  const float* inputs = (const float*)d_in[0];  // [2,2048,2048]
  const float* ln_w   = (const float*)d_in[1];  // [2048]
  const float* ln_b   = (const float*)d_in[2];  // [2048]
  const float* W1     = (const float*)d_in[3];  // [8192,2048]
  const float* b1     = (const float*)d_in[4];  // [8192]
  const float* W2     = (const float*)d_in[5];  // [2048,8192]
  const float* b2     = (const float*)d_in[6];  // [2048]
  float* out = (float*)d_out;                   // [2,2048,2048] fp32 (bf16-valued)
  char* ws = (char*)d_ws;
  (void)in_sizes; (void)n_in; (void)out_size; (void)ws_size;

  // workspace layout (144 MiB total)
  unsigned short* qW1  = (unsigned short*)(ws);                      // 32 MiB
  unsigned short* qW2  = (unsigned short*)(ws + (size_t)33554432);   // 32 MiB
  unsigned short* a1   = (unsigned short*)(ws + (size_t)67108864);   // 16 MiB [4096,2048]
  unsigned short* act2 = (unsigned short*)(ws + (size_t)83886080);   // 64 MiB [4096,8192]

  const int M = 4096;

  // 1. merged prep: quantize W1+W2 and LN+quant the activations (one dispatch)
  prep_k<<<20480, 256, 0, stream>>>(W1, W2, inputs, ln_w, ln_b, qW1, qW2, a1);

  // 2. GEMM1 + bias + gelu + fused MX quant (DPP) -> quantized bf16 [4096,8192]
  gemm_mx<1, 4><<<dim3(8192 / 256, M / 256), 512, 0, stream>>>(
      a1, qW1, M, 8192, 2048, b1, nullptr, (void*)act2);

  // 3. GEMM2 [4096,8192] x [2048,8192]^T + bias + residual -> fp32 out
  gemm_mx<2, 2><<<dim3(2048 / 128, M / 256), 512, 0, stream>>>(
      act2, qW2, M, 2048, 8192, b2, inputs, (void*)out);
}

// Round 4
// 514.164 us; speedup vs baseline: 1.0996x; 1.0996x over previous
//
#include <hip/hip_runtime.h>

#define DEVI __device__ __forceinline__

typedef __bf16 bf16x8 __attribute__((ext_vector_type(8)));
typedef float f32x4 __attribute__((ext_vector_type(4)));

#define WAIT_VM(n) asm volatile("s_waitcnt vmcnt(" #n ")" ::: "memory")

// ---------- exact bf16 RNE helpers ----------
DEVI unsigned short f2bf(float f) {
  unsigned u = __float_as_uint(f);
  u = (u + 0x7FFFu + ((u >> 16) & 1u)) >> 16;
  return (unsigned short)u;
}
DEVI float bf2f(unsigned short h) { return __uint_as_float(((unsigned)h) << 16); }
DEVI float bf16r(float f) { return bf2f(f2bf(f)); }

// ---------- fast MXINT8 scale from block amax (amax normal, >0) ----------
DEVI void mx_scales(float amax, float& scale, float& inv) {
  unsigned eb = __float_as_uint(amax) & 0x7f800000u;
  scale = __uint_as_float(eb - (6u << 23));          // 2^(e-6)
  inv   = __uint_as_float((260u << 23) - eb);        // 2^(6-e)
}

DEVI unsigned short quantv(float v, float scale, float inv) {
  float qv = rintf(v * inv);                          // RNE, matches jnp.round
  qv = fminf(fmaxf(qv, -128.f), 127.f);
  return f2bf(qv * scale);                            // exact in bf16
}

DEVI void quant8(const float* h, float amax, unsigned short* q) {
  if (amax > 0.f) {
    float scale, inv;
    mx_scales(amax, scale, inv);
#pragma unroll
    for (int k = 0; k < 8; ++k) q[k] = quantv(h[k], scale, inv);
  } else {
#pragma unroll
    for (int k = 0; k < 8; ++k) q[k] = 0;
  }
}

// ---------- 16-lane (DPP row) max reduction on the VALU pipe ----------
template <int N>
DEVI float qmax_step(float x) {
  int y = __builtin_amdgcn_update_dpp(0, __float_as_int(x), 0x120 | N, 0xF, 0xF, true);
  return fmaxf(x, __int_as_float(y));
}
DEVI float quad_row_max(float x) {
  x = qmax_step<1>(x);
  x = qmax_step<2>(x);
  x = qmax_step<4>(x);
  x = qmax_step<8>(x);
  return x;
}

// ---------- async global->LDS 16B ----------
DEVI void gl2lds16(const void* g, void* l) {
  __builtin_amdgcn_global_load_lds(
      (__attribute__((address_space(1))) void*)const_cast<void*>(g),
      (__attribute__((address_space(3))) void*)l, 16, 0, 0);
}

DEVI uint4 pack8(const unsigned short* q) {
  uint4 o;
  o.x = (unsigned)q[0] | ((unsigned)q[1] << 16);
  o.y = (unsigned)q[2] | ((unsigned)q[3] << 16);
  o.z = (unsigned)q[4] | ((unsigned)q[5] << 16);
  o.w = (unsigned)q[6] | ((unsigned)q[7] << 16);
  return o;
}

// ---------- merged prep: W1 quant | W2 quant | LN+quant in ONE dispatch ----------
__global__ __launch_bounds__(256) void prep_k(const float* __restrict__ W1,
                                              const float* __restrict__ W2,
                                              const float* __restrict__ X,
                                              const float* __restrict__ lw,
                                              const float* __restrict__ lb,
                                              unsigned short* __restrict__ qW1,
                                              unsigned short* __restrict__ qW2,
                                              unsigned short* __restrict__ a1) {
  __shared__ float red[4];
  const int bid = blockIdx.x;
  const int t = threadIdx.x;
  if (bid < 16384) {
    const float* src = (bid < 8192) ? W1 : W2;
    unsigned short* dst = (bid < 8192) ? qW1 : qW2;
    size_t idx = (size_t)(bid & 8191) * 256 + t;   // 8 elems/thread
    float4 v0 = ((const float4*)src)[idx * 2];
    float4 v1 = ((const float4*)src)[idx * 2 + 1];
    float h[8] = {v0.x, v0.y, v0.z, v0.w, v1.x, v1.y, v1.z, v1.w};
    float amax = 0.f;
#pragma unroll
    for (int k = 0; k < 8; ++k) amax = fmaxf(amax, fabsf(h[k]));
    amax = fmaxf(amax, __shfl_xor(amax, 1));   // 4 consecutive lanes = one 32-block
    amax = fmaxf(amax, __shfl_xor(amax, 2));
    unsigned short q[8];
    quant8(h, amax, q);
    ((uint4*)dst)[idx] = pack8(q);
  } else {
    const int H = 2048;
    const int row = bid - 16384;
    const int lane = t & 63, wave = t >> 6;
    const float* xr = X + (size_t)row * H;
    float4 v0 = ((const float4*)xr)[2 * t];
    float4 v1 = ((const float4*)xr)[2 * t + 1];
    float x[8] = {bf16r(v0.x), bf16r(v0.y), bf16r(v0.z), bf16r(v0.w),
                  bf16r(v1.x), bf16r(v1.y), bf16r(v1.z), bf16r(v1.w)};
    float s = 0.f;
#pragma unroll
    for (int k = 0; k < 8; ++k) s += x[k];
#pragma unroll
    for (int o = 32; o; o >>= 1) s += __shfl_xor(s, o);
    if (lane == 0) red[wave] = s;
    __syncthreads();
    float mu = (red[0] + red[1] + red[2] + red[3]) * (1.0f / H);
    __syncthreads();
    float v = 0.f;
#pragma unroll
    for (int k = 0; k < 8; ++k) { float d = x[k] - mu; v += d * d; }
#pragma unroll
    for (int o = 32; o; o >>= 1) v += __shfl_xor(v, o);
    if (lane == 0) red[wave] = v;
    __syncthreads();
    float var = (red[0] + red[1] + red[2] + red[3]) * (1.0f / H);
    float rstd = 1.0f / sqrtf(var + 1e-5f);
    float h[8];
    float amax = 0.f;
#pragma unroll
    for (int k = 0; k < 8; ++k) {
      int col = t * 8 + k;
      h[k] = bf16r((x[k] - mu) * rstd * lw[col] + lb[col]);
      amax = fmaxf(amax, fabsf(h[k]));
    }
    amax = fmaxf(amax, __shfl_xor(amax, 1));
    amax = fmaxf(amax, __shfl_xor(amax, 2));
    unsigned short q[8];
    quant8(h, amax, q);
    ((uint4*)(a1 + (size_t)row * H))[t] = pack8(q);
  }
}

// ============================================================================
// GEMM1: 256x256 tile, BK=64, 512 thr = 8 waves (2M x 4N), per-wave 128x64.
// m201-template schedule: 4 phases/K-tile, each phase = {read one subtile
// (8 or 4 ds_read_b128; B k-frags held in regs), stage 2 units, barrier,
// setprio1, 16 MFMA (compiler lgkm), setprio0, barrier}. 2 LDS buffers.
// Stage order (for tile t+1): ph1 Bu01, ph2 Bu23, ph3 Au0+Au2, ph4 Au1+Au3.
// Waits: vmcnt(4) before ph2's pre-MFMA barrier (guarantees Au1,Au3 of tile t
// for ph3 reads), vmcnt(2) before ph4's pre-MFMA barrier (guarantees B+Au0/2
// of tile t+1 for next ph1). Never drains to 0 in steady state.
// LDS layout = round-2 measured-zero-conflict: row 64 ushorts, chunk c of
// row r at pos c^(r&7); read chunk (ks*4+quad)^(lr&7); staging keeps LDS
// dest linear and inverse-swizzles the global source chunk.
// Epilogue MODE1: bf16(gelu(bf16(y+bias))) + fused DPP MX-quant -> bf16.
// ============================================================================
__global__ __launch_bounds__(512, 2) void gemm1_k(const unsigned short* __restrict__ A,
                                                  const unsigned short* __restrict__ B,
                                                  const float* __restrict__ bias,
                                                  unsigned short* __restrict__ outp) {
  constexpr int K = 2048, N = 8192, NT = K / 64;
  __shared__ __align__(16) unsigned short As[2 * 256 * 64];  // 64 KiB
  __shared__ __align__(16) unsigned short Bs[2 * 256 * 64];  // 64 KiB

  const int tid = threadIdx.x;
  const int lane = tid & 63;
  const int lr = lane & 15;
  const int quad = lane >> 4;
  const int wave = tid >> 6;
  const int wm = wave >> 2;          // 0..1
  const int wn = wave & 3;           // 0..3

  // XCD-bijective swizzle: 512 blocks, 8 XCDs -> 64 contiguous per XCD
  int lin = blockIdx.y * 32 + blockIdx.x;
  lin = (lin & 7) * 64 + (lin >> 3);
  const int m0 = (lin >> 5) * 256;
  const int n0 = (lin & 31) * 256;

  const int ch0 = quad ^ (lr & 7);               // k-step 0 chunk; k1 = ch0^4
  const int abase = (wm * 128 + lr) * 64;        // + mh*4096 + i*1024 + ch*8
  const int bbase = (wn * 64 + lr) * 64;         // + j*1024 + ch*8

  // staging: thread tid -> row u*64 + (tid>>3), pos tid&7, src chunk pos^(row&7)
  const int srow = tid >> 3;
  const int sch = (tid & 7) ^ (srow & 7);
  const size_t aoff = (size_t)(m0 + srow) * K + sch * 8;
  const size_t boff = (size_t)(n0 + srow) * K + sch * 8;
  const int lb = (tid & ~63) * 8;                // wave-uniform LDS base (ushorts)

  f32x4 acc[8][4];
#pragma unroll
  for (int i = 0; i < 8; ++i)
#pragma unroll
    for (int j = 0; j < 4; ++j) acc[i][j] = (f32x4){0.f, 0.f, 0.f, 0.f};

  // prologue: tile 0 -> buf 0 (order B0..3, A0,A2,A1,A3), drain, barrier
#pragma unroll
  for (int u = 0; u < 4; ++u) gl2lds16(B + boff + (size_t)u * 64 * K, Bs + u * 4096 + lb);
  gl2lds16(A + aoff + (size_t)0 * 64 * K, As + 0 * 4096 + lb);
  gl2lds16(A + aoff + (size_t)2 * 64 * K, As + 2 * 4096 + lb);
  gl2lds16(A + aoff + (size_t)1 * 64 * K, As + 1 * 4096 + lb);
  gl2lds16(A + aoff + (size_t)3 * 64 * K, As + 3 * 4096 + lb);
  WAIT_VM(0);
  __builtin_amdgcn_s_barrier();

  for (int t = 0; t < NT; ++t) {
    const int bb = (t & 1) * 16384;
    const int nbb = ((t + 1) & 1) * 16384;
    const bool pf = (t + 1) < NT;
    const size_t kadd = (size_t)(t + 1) * 64;
    const unsigned short* Ap = As + bb + abase;
    const unsigned short* Bp = Bs + bb + bbase;
    bf16x8 af[4], b0[4], b1[4];

    // ---- ph1: (mh0, k0) — read A(h0,k0) + B(k0); stage Bu0,Bu1 ----
#pragma unroll
    for (int i = 0; i < 4; ++i) af[i] = *(const bf16x8*)(Ap + ch0 * 8 + i * 1024);
#pragma unroll
    for (int j = 0; j < 4; ++j) b0[j] = *(const bf16x8*)(Bp + ch0 * 8 + j * 1024);
    if (pf) {
      gl2lds16(B + boff + kadd + (size_t)0 * 64 * K, Bs + nbb + 0 * 4096 + lb);
      gl2lds16(B + boff + kadd + (size_t)1 * 64 * K, Bs + nbb + 1 * 4096 + lb);
    }
    __builtin_amdgcn_s_barrier();
    __builtin_amdgcn_s_setprio(1);
#pragma unroll
    for (int i = 0; i < 4; ++i)
#pragma unroll
      for (int j = 0; j < 4; ++j)
        acc[i][j] = __builtin_amdgcn_mfma_f32_16x16x32_bf16(af[i], b0[j], acc[i][j], 0, 0, 0);
    __builtin_amdgcn_s_setprio(0);
    __builtin_amdgcn_s_barrier();

    // ---- ph2: (mh0, k1) — read A(h0,k1) + B(k1); stage Bu2,Bu3; vmcnt(4) ----
#pragma unroll
    for (int i = 0; i < 4; ++i) af[i] = *(const bf16x8*)(Ap + (ch0 ^ 4) * 8 + i * 1024);
#pragma unroll
    for (int j = 0; j < 4; ++j) b1[j] = *(const bf16x8*)(Bp + (ch0 ^ 4) * 8 + j * 1024);
    if (pf) {
      gl2lds16(B + boff + kadd + (size_t)2 * 64 * K, Bs + nbb + 2 * 4096 + lb);
      gl2lds16(B + boff + kadd + (size_t)3 * 64 * K, Bs + nbb + 3 * 4096 + lb);
      WAIT_VM(4);        // drains tile t's Au1,Au3 (needed by ph3 reads)
    } else {
      WAIT_VM(0);
    }
    __builtin_amdgcn_s_barrier();
    __builtin_amdgcn_s_setprio(1);
#pragma unroll
    for (int i = 0; i < 4; ++i)
#pragma unroll
      for (int j = 0; j < 4; ++j)
        acc[i][j] = __builtin_amdgcn_mfma_f32_16x16x32_bf16(af[i], b1[j], acc[i][j], 0, 0, 0);
    __builtin_amdgcn_s_setprio(0);
    __builtin_amdgcn_s_barrier();

    // ---- ph3: (mh1, k0) — read A(h1,k0); B(k0) kept; stage Au0,Au2 ----
#pragma unroll
    for (int i = 0; i < 4; ++i) af[i] = *(const bf16x8*)(Ap + 4096 + ch0 * 8 + i * 1024);
    if (pf) {
      gl2lds16(A + aoff + kadd + (size_t)0 * 64 * K, As + nbb + 0 * 4096 + lb);
      gl2lds16(A + aoff + kadd + (size_t)2 * 64 * K, As + nbb + 2 * 4096 + lb);
    }
    __builtin_amdgcn_s_barrier();
    __builtin_amdgcn_s_setprio(1);
#pragma unroll
    for (int i = 0; i < 4; ++i)
#pragma unroll
      for (int j = 0; j < 4; ++j)
        acc[4 + i][j] = __builtin_amdgcn_mfma_f32_16x16x32_bf16(af[i], b0[j], acc[4 + i][j], 0, 0, 0);
    __builtin_amdgcn_s_setprio(0);
    __builtin_amdgcn_s_barrier();

    // ---- ph4: (mh1, k1) — read A(h1,k1); stage Au1,Au3; vmcnt(2) ----
#pragma unroll
    for (int i = 0; i < 4; ++i) af[i] = *(const bf16x8*)(Ap + 4096 + (ch0 ^ 4) * 8 + i * 1024);
    if (pf) {
      gl2lds16(A + aoff + kadd + (size_t)1 * 64 * K, As + nbb + 1 * 4096 + lb);
      gl2lds16(A + aoff + kadd + (size_t)3 * 64 * K, As + nbb + 3 * 4096 + lb);
      WAIT_VM(2);        // drains tile t+1's B + Au0,Au2 (needed by next ph1)
    }
    __builtin_amdgcn_s_barrier();
    __builtin_amdgcn_s_setprio(1);
#pragma unroll
    for (int i = 0; i < 4; ++i)
#pragma unroll
      for (int j = 0; j < 4; ++j)
        acc[4 + i][j] = __builtin_amdgcn_mfma_f32_16x16x32_bf16(af[i], b1[j], acc[4 + i][j], 0, 0, 0);
    __builtin_amdgcn_s_setprio(0);
    __builtin_amdgcn_s_barrier();
  }

  // epilogue MODE1: D mapping col = lane&15, row = quad*4 + reg [m89-verified]
#pragma unroll
  for (int i = 0; i < 8; ++i) {
#pragma unroll
    for (int r = 0; r < 4; ++r) {
      const int gm = m0 + wm * 128 + i * 16 + quad * 4 + r;
      float g[4];
#pragma unroll
      for (int j = 0; j < 4; ++j) {
        float tt = bf16r(acc[i][j][r] + bias[n0 + wn * 64 + j * 16 + lr]);
        float u = 0.7978845608028654f * (tt + 0.044715f * tt * tt * tt);
        g[j] = bf16r(0.5f * tt * (1.0f + tanhf(u)));
      }
      float a = quad_row_max(fmaxf(fabsf(g[0]), fabsf(g[1])));
      float b = quad_row_max(fmaxf(fabsf(g[2]), fabsf(g[3])));
      unsigned short q[4];
      if (a > 0.f) {
        float sc2, iv; mx_scales(a, sc2, iv);
        q[0] = quantv(g[0], sc2, iv); q[1] = quantv(g[1], sc2, iv);
      } else { q[0] = q[1] = 0; }
      if (b > 0.f) {
        float sc2, iv; mx_scales(b, sc2, iv);
        q[2] = quantv(g[2], sc2, iv); q[3] = quantv(g[3], sc2, iv);
      } else { q[2] = q[3] = 0; }
      unsigned short* orow = outp + (size_t)gm * N + n0 + wn * 64 + lr;
#pragma unroll
      for (int j = 0; j < 4; ++j) orow[j * 16] = q[j];
    }
  }
}

// ============================================================================
// GEMM2: 128x256 tile, BK=64, 8 waves (2M x 4N), per-wave 64x64. 3 LDS bufs
// (144 KiB), stage tile t+2 during t (ph1: Bu0..3, ph2: Au0,Au1), single
// vmcnt(6) per tile (drains tile t+1's 6 units, keeps t+2's 6 in flight).
// 2 phases/K-tile (k-step 0/1), 16 MFMA each.
// Epilogue MODE2: out = bf16(bf16(resid) + bf16(y + bias)) -> float.
// ============================================================================
__global__ __launch_bounds__(512, 2) void gemm2_k(const unsigned short* __restrict__ A,
                                                  const unsigned short* __restrict__ B,
                                                  const float* __restrict__ bias,
                                                  const float* __restrict__ resid,
                                                  float* __restrict__ outp) {
  constexpr int K = 8192, N = 2048, NT = K / 64;
  __shared__ __align__(16) unsigned short As[3 * 128 * 64];  // 48 KiB
  __shared__ __align__(16) unsigned short Bs[3 * 256 * 64];  // 96 KiB

  const int tid = threadIdx.x;
  const int lane = tid & 63;
  const int lr = lane & 15;
  const int quad = lane >> 4;
  const int wave = tid >> 6;
  const int wm = wave >> 2;          // 0..1
  const int wn = wave & 3;           // 0..3

  // XCD-bijective swizzle: 256 blocks -> 32 contiguous per XCD
  int lin = blockIdx.y * 8 + blockIdx.x;
  lin = (lin & 7) * 32 + (lin >> 3);
  const int m0 = (lin >> 3) * 128;
  const int n0 = (lin & 7) * 256;

  const int ch0 = quad ^ (lr & 7);
  const int abase = (wm * 64 + lr) * 64;
  const int bbase = (wn * 64 + lr) * 64;

  const int srow = tid >> 3;
  const int sch = (tid & 7) ^ (srow & 7);
  const size_t aoff = (size_t)(m0 + srow) * K + sch * 8;
  const size_t boff = (size_t)(n0 + srow) * K + sch * 8;
  const int lb = (tid & ~63) * 8;

  f32x4 acc[4][4];
#pragma unroll
  for (int i = 0; i < 4; ++i)
#pragma unroll
    for (int j = 0; j < 4; ++j) acc[i][j] = (f32x4){0.f, 0.f, 0.f, 0.f};

  // prologue: stage tiles 0 (buf0) and 1 (buf1); drain tile 0 only
#pragma unroll
  for (int pt = 0; pt < 2; ++pt) {
    const size_t kadd = (size_t)pt * 64;
#pragma unroll
    for (int u = 0; u < 4; ++u)
      gl2lds16(B + boff + kadd + (size_t)u * 64 * K, Bs + pt * 16384 + u * 4096 + lb);
    gl2lds16(A + aoff + kadd + (size_t)0 * 64 * K, As + pt * 8192 + 0 * 4096 + lb);
    gl2lds16(A + aoff + kadd + (size_t)1 * 64 * K, As + pt * 8192 + 1 * 4096 + lb);
  }
  WAIT_VM(6);
  __builtin_amdgcn_s_barrier();

  int buf = 0;
  for (int t = 0; t < NT; ++t) {
    int nb = buf + 2; if (nb >= 3) nb -= 3;
    const bool pf = (t + 2) < NT;
    const size_t kadd = (size_t)(t + 2) * 64;
    const unsigned short* Ap = As + buf * 8192 + abase;
    const unsigned short* Bp = Bs + buf * 16384 + bbase;
    bf16x8 af[4], bq[4];

    // ---- ph1: k0 — read A(k0)+B(k0); stage Bu0..3 of tile t+2 ----
#pragma unroll
    for (int i = 0; i < 4; ++i) af[i] = *(const bf16x8*)(Ap + ch0 * 8 + i * 1024);
#pragma unroll
    for (int j = 0; j < 4; ++j) bq[j] = *(const bf16x8*)(Bp + ch0 * 8 + j * 1024);
    if (pf) {
#pragma unroll
      for (int u = 0; u < 4; ++u)
        gl2lds16(B + boff + kadd + (size_t)u * 64 * K, Bs + nb * 16384 + u * 4096 + lb);
    }
    __builtin_amdgcn_s_barrier();
    __builtin_amdgcn_s_setprio(1);
#pragma unroll
    for (int i = 0; i < 4; ++i)
#pragma unroll
      for (int j = 0; j < 4; ++j)
        acc[i][j] = __builtin_amdgcn_mfma_f32_16x16x32_bf16(af[i], bq[j], acc[i][j], 0, 0, 0);
    __builtin_amdgcn_s_setprio(0);
    __builtin_amdgcn_s_barrier();

    // ---- ph2: k1 — read A(k1)+B(k1); stage Au0,Au1; vmcnt(6) ----
#pragma unroll
    for (int i = 0; i < 4; ++i) af[i] = *(const bf16x8*)(Ap + (ch0 ^ 4) * 8 + i * 1024);
#pragma unroll
    for (int j = 0; j < 4; ++j) bq[j] = *(const bf16x8*)(Bp + (ch0 ^ 4) * 8 + j * 1024);
    if (pf) {
      gl2lds16(A + aoff + kadd + (size_t)0 * 64 * K, As + nb * 8192 + 0 * 4096 + lb);
      gl2lds16(A + aoff + kadd + (size_t)1 * 64 * K, As + nb * 8192 + 1 * 4096 + lb);
      WAIT_VM(6);        // drains tile t+1's 6 units; keeps t+2's 6 in flight
    } else if (t + 1 < NT) {
      WAIT_VM(0);        // tail: tile t+1 staged, nothing newer
    }
    __builtin_amdgcn_s_barrier();
    __builtin_amdgcn_s_setprio(1);
#pragma unroll
    for (int i = 0; i < 4; ++i)
#pragma unroll
      for (int j = 0; j < 4; ++j)
        acc[i][j] = __builtin_amdgcn_mfma_f32_16x16x32_bf16(af[i], bq[j], acc[i][j], 0, 0, 0);
    __builtin_amdgcn_s_setprio(0);
    __builtin_amdgcn_s_barrier();

    if (++buf == 3) buf = 0;
  }

  // epilogue MODE2
#pragma unroll
  for (int i = 0; i < 4; ++i) {
#pragma unroll
    for (int j = 0; j < 4; ++j) {
#pragma unroll
      for (int r = 0; r < 4; ++r) {
        int gm = m0 + wm * 64 + i * 16 + quad * 4 + r;
        int gn = n0 + wn * 64 + j * 16 + lr;
        float h = bf16r(acc[i][j][r] + bias[gn]);
        float rr = bf16r(resid[(size_t)gm * N + gn]);
        outp[(size_t)gm * N + gn] = bf16r(rr + h);
      }
    }
  }
}

extern "C" void kernel_launch(void* const* d_in, const int* in_sizes, int n_in,
                              void* d_out, int out_size, void* d_ws, size_t ws_size,
                              hipStream_t stream) {
  const float* inputs = (const float*)d_in[0];  // [2,2048,2048]
  const float* ln_w   = (const float*)d_in[1];  // [2048]
  const float* ln_b   = (const float*)d_in[2];  // [2048]
  const float* W1     = (const float*)d_in[3];  // [8192,2048]
  const float* b1     = (const float*)d_in[4];  // [8192]
  const float* W2     = (const float*)d_in[5];  // [2048,8192]
  const float* b2     = (const float*)d_in[6];  // [2048]
  float* out = (float*)d_out;                   // [2,2048,2048] fp32 (bf16-valued)
  char* ws = (char*)d_ws;
  (void)in_sizes; (void)n_in; (void)out_size; (void)ws_size;

  // workspace layout (144 MiB total)
  unsigned short* qW1  = (unsigned short*)(ws);                      // 32 MiB
  unsigned short* qW2  = (unsigned short*)(ws + (size_t)33554432);   // 32 MiB
  unsigned short* a1   = (unsigned short*)(ws + (size_t)67108864);   // 16 MiB [4096,2048]
  unsigned short* act2 = (unsigned short*)(ws + (size_t)83886080);   // 64 MiB [4096,8192]

  // 1. merged prep: quantize W1+W2 and LN+quant the activations (one dispatch)
  prep_k<<<20480, 256, 0, stream>>>(W1, W2, inputs, ln_w, ln_b, qW1, qW2, a1);

  // 2. GEMM1 + bias + gelu + fused MX quant (DPP) -> quantized bf16 [4096,8192]
  gemm1_k<<<dim3(8192 / 256, 4096 / 256), 512, 0, stream>>>(a1, qW1, b1, act2);

  // 3. GEMM2 [4096,8192] x [2048,8192]^T + bias + residual -> fp32 out
  gemm2_k<<<dim3(2048 / 256, 4096 / 128), 512, 0, stream>>>(act2, qW2, b2, inputs, out);
}